// Round 2
// 770.763 us; speedup vs baseline: 1.0025x; 1.0025x over previous
//
#include <hip/hip_runtime.h>
#include <hip/hip_bf16.h>
#include <stdint.h>

// ---------------------------------------------------------------------------
// PCAA bf16-MFMA, round 4b: vectorized convert_x (16B/lane loads+stores).
// B=4, C=K=512, H=W=128, bins=16, P=1024, Ci=256.
//
// Workspace (byte offsets):
//   0           wbf (6 weight mats bf16, 2,097,152 B)
//   2,097,152   bc  (32768 f32)
//   2,228,224   xpc [bn][p][c] bf16, 67,108,864 B   (live: conv..G9; aff after)
//   69,337,088  xcp [bn][c][p] bf16, 67,108,864 B   (live: conv..G3)
//       reuse:  g @69,337,088 (33.5MB) | lf @102,891,520 (33.5MB; attn later)
//   136,445,952 confb [bn][k][p] bf16 67MB (G1..G3); then globb/vt/key/query
//   203,554,816 localb bf16 33,554,432 B
// ---------------------------------------------------------------------------

typedef __attribute__((ext_vector_type(8))) short bfrag;
typedef __attribute__((ext_vector_type(4))) float ffrag;
typedef __hip_bfloat16 bf16;

__device__ __forceinline__ void load_lds16(const void* g, void* l) {
    __builtin_amdgcn_global_load_lds(
        (const __attribute__((address_space(1))) void*)(uintptr_t)g,
        (__attribute__((address_space(3))) void*)(uintptr_t)l,
        16, 0, 0);
}

// NT bf16 MFMA GEMM, 128x128 tile, BK=64, 4 waves of 64x64.
// 1D swizzled grid (see decode below): bins of a batch-z GEMM are pinned to
// one XCD (id%8 round-robin) so a bin's ~2MB working set stays in its L2;
// z==1 GEMMs group m-strips per XCD instead.
// EPI=0: bf16 out (+biasM/biasN, *scaleM).  EPI=1: BN+ReLU+residual, fp32
// NCHW out (G13: m=c, n=p, bt=bn).
template<int EPI>
__global__ void __launch_bounds__(256) gemm_bf16(
    const short* __restrict__ A, int aBatch,
    const short* __restrict__ B, int bBatch, int bShift,
    short* __restrict__ C, int cBatch,
    int M, int N, int K, int mT, int nT, int zTotal,
    const float* __restrict__ biasM, const float* __restrict__ biasN,
    const float* __restrict__ scaleM,
    const float* __restrict__ xres,
    const float* __restrict__ bng, const float* __restrict__ bnb,
    const float* __restrict__ bnm, const float* __restrict__ bnv)
{
    __shared__ short As[128 * 64];
    __shared__ short Bs[128 * 64];
    const int t = threadIdx.x;
    const int w = t >> 6, lane = t & 63;

    // ---- swizzled block decode ----
    const int id = blockIdx.x;
    const int T = mT * nT;
    int bt, mt, nt;
    if (zTotal >= 8) {                 // bin-per-XCD grouping (zTotal%8==0)
        const int x = id & 7, q = id >> 3;
        const int tile = q % T;
        bt = (q / T) * 8 + x;
        mt = tile / nT; nt = tile % nT;
    } else if (zTotal == 1 && (mT & 7) == 0) {  // m-strip-per-XCD grouping
        const int x = id & 7, q = id >> 3;
        nt = q % nT;
        mt = x * (mT >> 3) + q / nT;
        bt = 0;
    } else {
        bt = id / T;
        const int tile = id % T;
        mt = tile / nT; nt = tile % nT;
    }
    const int m0 = mt * 128, n0 = nt * 128;

    const short* gA = A + (size_t)bt * aBatch;
    const short* gB = B + (size_t)(bt >> bShift) * bBatch;
    const int wm = w >> 1, wn = w & 1;

    ffrag acc[4][4] = {};

    const int rowbase = w * 32;
    const int lr = lane >> 3;
    const int lc = lane & 7;

    for (int k0 = 0; k0 < K; k0 += 64) {
#pragma unroll
        for (int j = 0; j < 4; ++j) {
            const int rr = rowbase + j * 8 + lr;
            const int ch = lc ^ (rr & 7);
            load_lds16(gA + (size_t)(m0 + rr) * K + k0 + ch * 8,
                       &As[(rowbase + j * 8) * 64]);
            load_lds16(gB + (size_t)(n0 + rr) * K + k0 + ch * 8,
                       &Bs[(rowbase + j * 8) * 64]);
        }
        __syncthreads();
#pragma unroll
        for (int kk = 0; kk < 2; ++kk) {
            bfrag af[4], bfv[4];
#pragma unroll
            for (int i = 0; i < 4; ++i) {
                const int ra = wm * 64 + i * 16 + (lane & 15);
                const int cl = kk * 4 + (lane >> 4);
                af[i]  = *(const bfrag*)&As[ra * 64 + ((cl ^ (ra & 7)) * 8)];
                const int rb = wn * 64 + i * 16 + (lane & 15);
                bfv[i] = *(const bfrag*)&Bs[rb * 64 + ((cl ^ (rb & 7)) * 8)];
            }
#pragma unroll
            for (int i = 0; i < 4; ++i)
#pragma unroll
                for (int j = 0; j < 4; ++j)
                    acc[i][j] = __builtin_amdgcn_mfma_f32_16x16x32_bf16(
                        af[i], bfv[j], acc[i][j], 0, 0, 0);
        }
        __syncthreads();
    }

    if (EPI == 0) {
        bf16* gC = (bf16*)(C + (size_t)bt * cBatch);
#pragma unroll
        for (int i = 0; i < 4; ++i) {
#pragma unroll
            for (int j = 0; j < 4; ++j) {
                const int col = n0 + wn * 64 + j * 16 + (lane & 15);
                const float bnvl = biasN ? biasN[col] : 0.f;
#pragma unroll
                for (int r = 0; r < 4; ++r) {
                    const int row = m0 + wm * 64 + i * 16 + (lane >> 4) * 4 + r;
                    float v = acc[i][j][r] + bnvl + (biasM ? biasM[row] : 0.f);
                    if (scaleM) v *= scaleM[bt * M + row];
                    gC[(size_t)row * N + col] = __float2bfloat16(v);
                }
            }
        }
    } else {
        // G13: rows = c, cols = p, bt = bn. out = x + relu(bn(acc)), fp32 NCHW.
        float* O = (float*)C;
        const int b = bt >> 4, binq = bt & 15;
        const int h0 = (binq >> 2) * 32, w0 = (binq & 3) * 32;
#pragma unroll
        for (int i = 0; i < 4; ++i) {
#pragma unroll
            for (int r = 0; r < 4; ++r) {
                const int c = m0 + wm * 64 + i * 16 + (lane >> 4) * 4 + r;
                const float sc = bng[c] * rsqrtf(bnv[c] + 1e-5f);
                const float mm = bnm[c], bb = bnb[c];
#pragma unroll
                for (int j = 0; j < 4; ++j) {
                    const int p = n0 + wn * 64 + j * 16 + (lane & 15);
                    const size_t flat =
                        (((size_t)b * 512 + c) * 128 + h0 + (p >> 5)) * 128
                        + w0 + (p & 31);
                    O[flat] = xres[flat]
                        + fmaxf(fmaf(acc[i][j][r] - mm, sc, bb), 0.f);
                }
            }
        }
    }
}

// fp32 -> bf16 for the 6 weight matrices, packed contiguously into wbf.
__global__ void __launch_bounds__(256) wconv(
    const float* __restrict__ wc, const float* __restrict__ wg2,
    const float* __restrict__ wq, const float* __restrict__ wk,
    const float* __restrict__ wv, const float* __restrict__ wo,
    bf16* __restrict__ dst)
{
    const int i = blockIdx.x * 256 + threadIdx.x;   // 1,048,576 total
    const float* s; int o;
    if      (i <  262144) { s = wc;  o = i; }
    else if (i <  524288) { s = wg2; o = i - 262144; }
    else if (i <  655360) { s = wq;  o = i - 524288; }
    else if (i <  786432) { s = wk;  o = i - 655360; }
    else if (i <  917504) { s = wv;  o = i - 786432; }
    else                  { s = wo;  o = i - 917504; }
    dst[i] = __float2bfloat16(s[o]);
}

// x NCHW fp32 -> xpc[bn][p][c] bf16 and xcp[bn][c][p] bf16.
// Round-4 rewrite: 16B/lane vectorized global loads (2x float4) and stores
// (short8) on BOTH outputs; f32 LDS transpose tile 64c x 32p, pad 33
// (2-way-max bank aliasing on both phases == free per m136).
// Grid: (bn=64, ct=8 [64 c each], ph=32). Block 256.
__global__ void __launch_bounds__(256) convert_x(
    const float* __restrict__ x, bf16* __restrict__ xpc, bf16* __restrict__ xcp)
{
    const int bn = blockIdx.x, ct = blockIdx.y, ph = blockIdx.z;
    const int b = bn >> 4, n = bn & 15;
    const int c0 = ct * 64;
    const int h = (n >> 2) * 32 + ph;
    const int w0 = (n & 3) * 32;
    const int p0 = ph * 32;
    __shared__ float tile[64][33];      // [c][pw], pad->2-way max
    const int t = threadIdx.x;

    // Phase 1: load 64c x 32w; thread owns c = c0+(t>>2), 8 w at (t&3)*8.
    // Writes xcp[bn][c][p] (p contiguous) as one 16B store.
    {
        const int ci = t >> 2;          // 0..63
        const int wc = (t & 3) * 8;     // 0,8,16,24
        const float* src =
            &x[(((size_t)b * 512 + c0 + ci) * 128 + h) * 128 + w0 + wc];
        const float4 v0 = *(const float4*)src;
        const float4 v1 = *(const float4*)(src + 4);
        float* td = &tile[ci][wc];
        td[0] = v0.x; td[1] = v0.y; td[2] = v0.z; td[3] = v0.w;
        td[4] = v1.x; td[5] = v1.y; td[6] = v1.z; td[7] = v1.w;
        bf16 tmp[8];
        tmp[0] = __float2bfloat16(v0.x);
        tmp[1] = __float2bfloat16(v0.y);
        tmp[2] = __float2bfloat16(v0.z);
        tmp[3] = __float2bfloat16(v0.w);
        tmp[4] = __float2bfloat16(v1.x);
        tmp[5] = __float2bfloat16(v1.y);
        tmp[6] = __float2bfloat16(v1.z);
        tmp[7] = __float2bfloat16(v1.w);
        *(bfrag*)&xcp[((size_t)bn * 512 + c0 + ci) * 1024 + p0 + wc] =
            *(const bfrag*)tmp;
    }
    __syncthreads();

    // Phase 2: thread owns p = p0+(t>>3), 8 c at (t&7)*8; one 16B store
    // to xpc[bn][p][c] (c contiguous).
    {
        const int pi = t >> 3;          // 0..31
        const int cc = (t & 7) * 8;     // 0..56
        bf16 tmp[8];
#pragma unroll
        for (int i = 0; i < 8; ++i)
            tmp[i] = __float2bfloat16(tile[cc + i][pi]);
        *(bfrag*)&xpc[((size_t)bn * 1024 + p0 + pi) * 512 + c0 + cc] =
            *(const bfrag*)tmp;
    }
}

// per-row (1024 px) softmax in place on bf16 + binconf = sigmoid(mean)
__global__ void __launch_bounds__(256) softmax_pool_1024(
    bf16* __restrict__ conf, float* __restrict__ binconf)
{
    const int row = blockIdx.x;             // bn*512 + k
    bf16* r = conf + (size_t)row * 1024;
    const int t = threadIdx.x;
    bf16 a[4];
    *(uint2*)a = *(const uint2*)(r + t * 4);
    float f[4];
#pragma unroll
    for (int i = 0; i < 4; ++i) f[i] = __bfloat162float(a[i]);
    float s  = f[0] + f[1] + f[2] + f[3];
    float mx = fmaxf(fmaxf(f[0], f[1]), fmaxf(f[2], f[3]));
#pragma unroll
    for (int off = 32; off > 0; off >>= 1) {
        s += __shfl_down(s, off, 64);
        mx = fmaxf(mx, __shfl_down(mx, off, 64));
    }
    __shared__ float rs[4], rm[4], re[4];
    const int wv = t >> 6, ln = t & 63;
    if (ln == 0) { rs[wv] = s; rm[wv] = mx; }
    __syncthreads();
    const float MX = fmaxf(fmaxf(rm[0], rm[1]), fmaxf(rm[2], rm[3]));
    if (t == 0) {
        const float mean = (rs[0] + rs[1] + rs[2] + rs[3]) * (1.f / 1024.f);
        binconf[row] = 1.f / (1.f + __expf(-mean));
    }
    float e[4];
#pragma unroll
    for (int i = 0; i < 4; ++i) e[i] = __expf(f[i] - MX);
    float es = e[0] + e[1] + e[2] + e[3];
#pragma unroll
    for (int off = 32; off > 0; off >>= 1) es += __shfl_down(es, off, 64);
    if (ln == 0) re[wv] = es;
    __syncthreads();
    const float inv = 1.f / (re[0] + re[1] + re[2] + re[3]);
#pragma unroll
    for (int i = 0; i < 4; ++i) a[i] = __float2bfloat16(e[i] * inv);
    *(uint2*)(r + t * 4) = *(uint2*)a;
}

// softmax over last dim (512), one wave per row, in place, bf16
__global__ void __launch_bounds__(256) softmax_rows_512(bf16* __restrict__ aff)
{
    const int t = threadIdx.x;
    const int wv = t >> 6, ln = t & 63;
    const int row = blockIdx.x * 4 + wv;
    bf16* r = aff + (size_t)row * 512;
    bf16 a[8];
    *(uint4*)a = *(const uint4*)(r + ln * 8);
    float f[8];
#pragma unroll
    for (int i = 0; i < 8; ++i) f[i] = __bfloat162float(a[i]);
    float mx = f[0];
#pragma unroll
    for (int i = 1; i < 8; ++i) mx = fmaxf(mx, f[i]);
#pragma unroll
    for (int off = 32; off > 0; off >>= 1) mx = fmaxf(mx, __shfl_down(mx, off, 64));
    mx = __shfl(mx, 0, 64);
    float es = 0.f;
#pragma unroll
    for (int i = 0; i < 8; ++i) { f[i] = __expf(f[i] - mx); es += f[i]; }
#pragma unroll
    for (int off = 32; off > 0; off >>= 1) es += __shfl_down(es, off, 64);
    es = __shfl(es, 0, 64);
    const float inv = 1.f / es;
#pragma unroll
    for (int i = 0; i < 8; ++i) a[i] = __float2bfloat16(f[i] * inv);
    *(uint4*)(r + ln * 8) = *(uint4*)a;
}

// g[b][n][k][c] = relu(sum_m w1[n][m]*local[b][m][k][c] + local[b][n][k][c])
__global__ void __launch_bounds__(256) gcn1_kernel(
    const bf16* __restrict__ localb, bf16* __restrict__ g,
    const float* __restrict__ w_gcn1)
{
    __shared__ float wsm[16][16];
    const int t = threadIdx.x;
    wsm[t >> 4][t & 15] = w_gcn1[t];
    const int idx = blockIdx.x * 256 + t;
    const int b  = idx >> 18;               // K*C = 262144
    const int kc = idx & 262143;
    const bf16* lp = localb + (size_t)b * 4194304 + kc;
    __syncthreads();
    float lv[16];
#pragma unroll
    for (int m = 0; m < 16; ++m) lv[m] = __bfloat162float(lp[m * 262144]);
    bf16* gp = g + (size_t)b * 4194304 + kc;
#pragma unroll
    for (int n = 0; n < 16; ++n) {
        float acc = lv[n];
#pragma unroll
        for (int m = 0; m < 16; ++m) acc = fmaf(wsm[n][m], lv[m], acc);
        gp[n * 262144] = __float2bfloat16(fmaxf(acc, 0.f));
    }
}

// glob[b][k][c] = relu(sum_m w_fuse[m]*lfeats[b][m][k][c] + b_fuse)
__global__ void __launch_bounds__(256) glob_kernel(
    const bf16* __restrict__ lfeats, bf16* __restrict__ glob,
    const float* __restrict__ w_fuse, const float* __restrict__ b_fuse)
{
    const int idx = blockIdx.x * 256 + threadIdx.x;
    const int b  = idx >> 18;
    const int kc = idx & 262143;
    const bf16* lp = lfeats + (size_t)b * 4194304 + kc;
    float acc = b_fuse[0];
#pragma unroll
    for (int m = 0; m < 16; ++m)
        acc = fmaf(w_fuse[m], __bfloat162float(lp[m * 262144]), acc);
    glob[idx] = __float2bfloat16(fmaxf(acc, 0.f));
}

extern "C" void kernel_launch(void* const* d_in, const int* in_sizes, int n_in,
                              void* d_out, int out_size, void* d_ws, size_t ws_size,
                              hipStream_t stream) {
    (void)in_sizes; (void)n_in; (void)out_size; (void)ws_size;
    const float* x      = (const float*)d_in[0];
    const float* w_cam  = (const float*)d_in[1];
    const float* b_cam  = (const float*)d_in[2];
    const float* w_gcn1 = (const float*)d_in[3];
    const float* w_gcn2 = (const float*)d_in[4];
    const float* w_fuse = (const float*)d_in[5];
    const float* b_fuse = (const float*)d_in[6];
    const float* w_q    = (const float*)d_in[7];
    const float* b_q    = (const float*)d_in[8];
    const float* w_k    = (const float*)d_in[9];
    const float* b_k    = (const float*)d_in[10];
    const float* w_v    = (const float*)d_in[11];
    const float* b_v    = (const float*)d_in[12];
    const float* w_out  = (const float*)d_in[13];
    const float* bng    = (const float*)d_in[14];
    const float* bnb    = (const float*)d_in[15];
    const float* bnm    = (const float*)d_in[16];
    const float* bnv    = (const float*)d_in[17];

    char* base = (char*)d_ws;
    bf16*  wbf    = (bf16*)(base);
    float* bc     = (float*)(base + 2097152);
    bf16*  xpc    = (bf16*)(base + 2228224);
    bf16*  xcp    = (bf16*)(base + 69337088);
    bf16*  confb  = (bf16*)(base + 136445952);
    bf16*  localb = (bf16*)(base + 203554816);
    bf16*  g      = xcp;                        // xcp dead after G3
    bf16*  lf     = (bf16*)(base + 102891520);
    bf16*  globb  = confb;                      // confb dead after G3
    bf16*  vt     = (bf16*)(base + 138543104);
    bf16*  key    = (bf16*)(base + 139067392);
    bf16*  query  = (bf16*)(base + 155844608);
    bf16*  aff    = xpc;                        // xpc dead after G9
    bf16*  attn   = lf;                         // lf dead after G8

    bf16* wcam = wbf;
    bf16* wg2  = wbf + 262144;
    bf16* wq   = wbf + 524288;
    bf16* wk   = wbf + 655360;
    bf16* wv   = wbf + 786432;
    bf16* wo   = wbf + 917504;

    wconv<<<4096, 256, 0, stream>>>(w_cam, w_gcn2, w_q, w_k, w_v, w_out, wbf);
    convert_x<<<dim3(64, 8, 32), 256, 0, stream>>>(x, xpc, xcp);

    // 1) cam[bn][k][p] = w_cam . xpc + b_cam     M=512 N=1024 K=512 z=64
    gemm_bf16<0><<<4 * 8 * 64, 256, 0, stream>>>(
        (const short*)wcam, 0, (const short*)xpc, 524288, 0,
        (short*)confb, 524288, 512, 1024, 512, 4, 8, 64,
        b_cam, nullptr, nullptr, nullptr, nullptr, nullptr, nullptr, nullptr);
    // 2) pixel softmax (in place) + bin confidence
    softmax_pool_1024<<<32768, 256, 0, stream>>>(confb, bc);
    // 3) local[bn][k][c] = (conf . xcp) * bc     M=512 N=512 K=1024 z=64
    gemm_bf16<0><<<4 * 4 * 64, 256, 0, stream>>>(
        (const short*)confb, 524288, (const short*)xcp, 524288, 0,
        (short*)localb, 262144, 512, 512, 1024, 4, 4, 64,
        nullptr, nullptr, bc, nullptr, nullptr, nullptr, nullptr, nullptr);
    // 4) g = relu(w_gcn1 @ local + local)
    gcn1_kernel<<<4096, 256, 0, stream>>>(localb, g, w_gcn1);
    // 5) lfeats[bnk][d] = g . w_gcn2             M=32768 N=512 K=512 z=1
    gemm_bf16<0><<<256 * 4, 256, 0, stream>>>(
        (const short*)g, 0, (const short*)wg2, 0, 0,
        (short*)lf, 0, 32768, 512, 512, 256, 4, 1,
        nullptr, nullptr, nullptr, nullptr, nullptr, nullptr, nullptr, nullptr);
    // 6) glob = relu(w_fuse . lfeats + b_fuse)
    glob_kernel<<<4096, 256, 0, stream>>>(lf, globb, w_fuse, b_fuse);
    // 7) vt[b][i][k] = w_v . glob + b_v          M=256 N=512 K=512 z=4
    gemm_bf16<0><<<2 * 4 * 4, 256, 0, stream>>>(
        (const short*)wv, 0, (const short*)globb, 262144, 0,
        (short*)vt, 131072, 256, 512, 512, 2, 4, 4,
        b_v, nullptr, nullptr, nullptr, nullptr, nullptr, nullptr, nullptr);
    // 8) key[bnk][i] = lfeats . w_k + b_k        M=32768 N=256 K=512 z=1
    gemm_bf16<0><<<256 * 2, 256, 0, stream>>>(
        (const short*)lf, 0, (const short*)wk, 0, 0,
        (short*)key, 0, 32768, 256, 512, 256, 2, 1,
        nullptr, b_k, nullptr, nullptr, nullptr, nullptr, nullptr, nullptr);
    // 9) query[bn][p][i] = xpc . w_q + b_q       M=1024 N=256 K=512 z=64
    gemm_bf16<0><<<8 * 2 * 64, 256, 0, stream>>>(
        (const short*)xpc, 524288, (const short*)wq, 0, 0,
        (short*)query, 262144, 1024, 256, 512, 8, 2, 64,
        nullptr, b_q, nullptr, nullptr, nullptr, nullptr, nullptr, nullptr);
    // 10) aff[bn][p][k] = query . key            M=1024 N=512 K=256 z=64
    gemm_bf16<0><<<8 * 4 * 64, 256, 0, stream>>>(
        (const short*)query, 262144, (const short*)key, 131072, 0,
        (short*)aff, 524288, 1024, 512, 256, 8, 4, 64,
        nullptr, nullptr, nullptr, nullptr, nullptr, nullptr, nullptr, nullptr);
    // 11) softmax over k (in place)
    softmax_rows_512<<<16384, 256, 0, stream>>>(aff);
    // 12) attn[bn][p][i] = aff . vt[b]           M=1024 N=256 K=512 z=64
    gemm_bf16<0><<<8 * 2 * 64, 256, 0, stream>>>(
        (const short*)aff, 524288, (const short*)vt, 131072, 4,
        (short*)attn, 262144, 1024, 256, 512, 8, 2, 64,
        nullptr, nullptr, nullptr, nullptr, nullptr, nullptr, nullptr, nullptr);
    // 13) y = w_out . attn, fused BN+ReLU+residual, fp32 NCHW out
    //     M=512(c) N=1024(p) K=256 z=64
    gemm_bf16<1><<<4 * 8 * 64, 256, 0, stream>>>(
        (const short*)wo, 0, (const short*)attn, 262144, 0,
        (short*)d_out, 0, 512, 1024, 256, 4, 8, 64,
        nullptr, nullptr, nullptr, x, bng, bnb, bnm, bnv);
}